// Round 9
// baseline (1232.417 us; speedup 1.0000x reference)
//
#include <hip/hip_runtime.h>

#define NNODES 100000
#define NEDGES 1600000
#define NGRAPHS 64
#define HID 128
#define OUTD 256
#define NLAYERS 5
#define BN_EPS 1e-5f
#define NBUCK 196          // ceil(NNODES/512)
#define BUCKCAP 9216       // avg 8192 edges/bucket + 11 sigma
#define FILL_BLOCKS 391    // ceil(NEDGES/4096)
#define NREP1 64           // stats replicas for fused agg+gemm1
#define NREP2 8            // stats replicas for gemm2 (782 blocks)
#define AG1B 6250          // NNODES/16 fused agg+gemm1 blocks

typedef __attribute__((ext_vector_type(8))) short short8;
typedef __attribute__((ext_vector_type(4))) float f32x4;

__device__ inline unsigned short f2b(float f) {
    union { float f; unsigned int u; } a; a.f = f;
    unsigned int u = a.u;
    return (unsigned short)((u + 0x7FFF + ((u >> 16) & 1)) >> 16);  // RNE
}
__device__ inline float b2f(unsigned short b) {
    union { unsigned int u; float f; } a; a.u = ((unsigned int)b) << 16;
    return a.f;
}

union U8 { short8 v; unsigned short u[8]; };

// -------- init: h = x (fp32), hb = bf16(x) row-major; W^T; bcur -------------
__global__ void k_init(const float* __restrict__ x, float* __restrict__ h,
                       ushort* __restrict__ hb,
                       const float* __restrict__ w1, const float* __restrict__ w2,
                       unsigned short* __restrict__ WT, int* __restrict__ bcur) {
    int b = blockIdx.x;
    if (b < 12500) {
        int i = b * 256 + threadIdx.x;  // float4 index
        float4 v = ((const float4*)x)[i];
        ((float4*)h)[i] = v;
        ushort4 o;
        o.x = f2b(v.x); o.y = f2b(v.y); o.z = f2b(v.z); o.w = f2b(v.w);
        ((ushort4*)hb)[i] = o;
    } else {
        int t = (b - 12500) * 256 + threadIdx.x;
        int mat = t >> 14;
        int rem = t & 16383;
        int k = rem >> 7, n = rem & 127;
        const float* src = (mat < 5) ? &w1[(size_t)mat * 16384]
                                     : &w2[(size_t)(mat - 5) * 16384];
        WT[(size_t)mat * 16384 + n * 128 + k] = f2b(src[k * 128 + n]);
        if (b == 12500 && threadIdx.x < NBUCK)
            bcur[threadIdx.x] = threadIdx.x * BUCKCAP;
    }
}

// ---------------- CSR build (bucketed, no global per-node histogram) --------
__global__ __launch_bounds__(256) void k_fill1(
    const int* __restrict__ srcv, const int* __restrict__ dstv,
    int* __restrict__ bcur, unsigned int* __restrict__ packed) {
    __shared__ int hist[NBUCK];
    __shared__ int base[NBUCK];
    int tid = threadIdx.x;
    int e0 = blockIdx.x * 4096;
    for (int i = tid; i < NBUCK; i += 256) hist[i] = 0;
    __syncthreads();
#pragma unroll
    for (int i = 0; i < 16; i++) {
        int e = e0 + i * 256 + tid;
        if (e < NEDGES) atomicAdd(&hist[dstv[e] >> 9], 1);
    }
    __syncthreads();
    for (int i = tid; i < NBUCK; i += 256) {
        int c = hist[i];
        base[i] = c ? atomicAdd(&bcur[i], c) : 0;
        hist[i] = 0;
    }
    __syncthreads();
#pragma unroll
    for (int i = 0; i < 16; i++) {
        int e = e0 + i * 256 + tid;
        if (e < NEDGES) {
            int d = dstv[e];
            int b = d >> 9;
            int r = atomicAdd(&hist[b], 1);
            packed[base[b] + r] = ((unsigned int)srcv[e] << 9) | (unsigned int)(d & 511);
        }
    }
}

// Phase 2 + degree histogram (padded bins: dhist[d*16])
__global__ __launch_bounds__(256) void k_fill2(
    const unsigned int* __restrict__ packed, const int* __restrict__ bcur,
    int2* __restrict__ off2, int* __restrict__ adj, int* __restrict__ dhist) {
    __shared__ int deg[512];
    __shared__ int cur[512];
    __shared__ int dh[64];
    int tid = threadIdx.x;
    int b = blockIdx.x;
    int base = b * BUCKCAP;
    int cnt = bcur[b] - base;
    deg[tid] = 0; deg[tid + 256] = 0;
    if (tid < 64) dh[tid] = 0;
    __syncthreads();
    for (int i = tid; i < cnt; i += 256)
        atomicAdd(&deg[packed[base + i] & 511], 1);
    __syncthreads();
    cur[tid] = deg[tid]; cur[tid + 256] = deg[tid + 256];
    __syncthreads();
    for (int o = 1; o < 512; o <<= 1) {
        int u0 = (tid >= o) ? cur[tid - o] : 0;
        int u1 = (tid + 256 >= o) ? cur[tid + 256 - o] : 0;
        __syncthreads();
        cur[tid] += u0; cur[tid + 256] += u1;
        __syncthreads();
    }
    int nbase = b * 512;
#pragma unroll
    for (int i = 0; i < 2; i++) {
        int t = tid + i * 256;
        int st = base + cur[t] - deg[t];   // exclusive scan + bucket base
        int n = nbase + t;
        if (n < NNODES) {
            off2[n] = make_int2(st, st + deg[t]);
            int d = deg[t]; if (d > 63) d = 63;
            atomicAdd(&dh[d], 1);
        }
    }
    __syncthreads();
    if (tid < 64 && dh[tid]) atomicAdd(&dhist[tid * 16], dh[tid]);
#pragma unroll
    for (int i = 0; i < 2; i++) {
        int t = tid + i * 256;
        cur[t] = base + cur[t] - deg[t];   // absolute cursors
    }
    __syncthreads();
    for (int i = tid; i < cnt; i += 256) {
        unsigned int p = packed[base + i];
        int r = atomicAdd(&cur[p & 511], 1);
        adj[r] = (int)(p >> 9);
    }
}

// exclusive prefix over 64 degree bins -> padded cursors
__global__ void k_dscan(const int* __restrict__ dhist, int* __restrict__ dcur) {
    if (threadIdx.x == 0) {
        int s = 0;
        for (int i = 0; i < 64; i++) { int c = dhist[i * 16]; dcur[i * 16] = s; s += c; }
    }
}

// scatter nodes into degree-sorted perm (LDS-aggregated, padded cursors)
__global__ __launch_bounds__(256) void k_dscat(
    const int2* __restrict__ off2, int* __restrict__ dcur, int* __restrict__ perm) {
    __shared__ int h[64], base[64];
    int tid = threadIdx.x;
    int n = blockIdx.x * 256 + tid;
    if (tid < 64) h[tid] = 0;
    __syncthreads();
    int d = 0;
    if (n < NNODES) {
        int2 oo = off2[n];
        d = oo.y - oo.x; if (d > 63) d = 63;
        atomicAdd(&h[d], 1);
    }
    __syncthreads();
    if (tid < 64) { int c = h[tid]; base[tid] = c ? atomicAdd(&dcur[tid * 16], c) : 0; h[tid] = 0; }
    __syncthreads();
    if (n < NNODES) {
        int r = atomicAdd(&h[d], 1);
        perm[base[d] + r] = n;
    }
}

// ---- fused agg+GEMM1, barrier-free: per-wave shfl-built A-frags -------------
// Gather unchanged (16 lanes/node, 4 nodes/wave). A-frag for the 16x16x32 MFMA
// is built from the wave's own registers via __shfl (lane q*16+r needs row r&3,
// chunk kc*4+q, held by lane (r&3)*16 + kc*4+q). Rows 4-15 are duplicates of
// rows 0-3 (valid data, outputs discarded). No LDS, no __syncthreads.
__global__ __launch_bounds__(256) void k_ag1(
    const ushort* __restrict__ hb, const int2* __restrict__ off2,
    const int* __restrict__ adj, const int* __restrict__ perm,
    const unsigned short* __restrict__ WT,
    const float* __restrict__ bias, ushort* __restrict__ C,
    float* __restrict__ stats) {
    int tid = threadIdx.x;
    int wave = tid >> 6;
    int lane = tid & 63;
    int c = lane & 15;                  // 16B chunk of the 256B row
    int node = perm[blockIdx.x * 16 + (tid >> 4)];   // tid>>4 = wave*4 + j
    const short8* hb8 = (const short8*)hb;

    U8 sv; sv.v = hb8[(size_t)node * 16 + c];
    float acc[8];
#pragma unroll
    for (int k = 0; k < 8; k++) acc[k] = b2f(sv.u[k]);

    int2 oo = off2[node];
    int e = oo.x, e1 = oo.y;
    for (; e + 8 <= e1; e += 8) {
        int s[8];
#pragma unroll
        for (int j = 0; j < 8; j++) s[j] = adj[e + j];
        U8 u[8];
#pragma unroll
        for (int j = 0; j < 8; j++) u[j].v = hb8[(size_t)s[j] * 16 + c];
#pragma unroll
        for (int j = 0; j < 8; j++)
#pragma unroll
            for (int k = 0; k < 8; k++) acc[k] += b2f(u[j].u[k]);
    }
    for (; e + 4 <= e1; e += 4) {
        int s0 = adj[e], s1 = adj[e + 1], s2 = adj[e + 2], s3 = adj[e + 3];
        U8 u0, u1, u2, u3;
        u0.v = hb8[(size_t)s0 * 16 + c];
        u1.v = hb8[(size_t)s1 * 16 + c];
        u2.v = hb8[(size_t)s2 * 16 + c];
        u3.v = hb8[(size_t)s3 * 16 + c];
#pragma unroll
        for (int k = 0; k < 8; k++)
            acc[k] += (b2f(u0.u[k]) + b2f(u1.u[k])) + (b2f(u2.u[k]) + b2f(u3.u[k]));
    }
    for (; e < e1; e++) {
        int s = adj[e];
        U8 u; u.v = hb8[(size_t)s * 16 + c];
#pragma unroll
        for (int k = 0; k < 8; k++) acc[k] += b2f(u.u[k]);
    }

    // z for this lane's (node, chunk) as 4 dwords
    union { short8 v; unsigned int d[4]; } ob;
    U8 o;
#pragma unroll
    for (int k = 0; k < 8; k++) o.u[k] = f2b(acc[k]);
    ob.v = o.v;

    // ---- per-wave GEMM: 4 valid rows x 128 cols, 32 MFMAs -----------------
    int qt = lane >> 4;                 // k-chunk group in MFMA layout
    int rt = lane & 15;                 // row in MFMA layout (valid: rt<4)

    f32x4 gacc[8];
#pragma unroll
    for (int nt = 0; nt < 8; nt++) gacc[nt] = (f32x4){0.f, 0.f, 0.f, 0.f};

#pragma unroll
    for (int kc = 0; kc < 4; kc++) {
        int src = ((rt & 3) << 4) + kc * 4 + qt;   // source lane in gather layout
        union { unsigned int d[4]; short8 v; } av;
#pragma unroll
        for (int d = 0; d < 4; d++) av.d[d] = __shfl((int)ob.d[d], src, 64);
        int k0 = kc * 32 + qt * 8;
#pragma unroll
        for (int nt = 0; nt < 8; nt++) {
            short8 bf = *(const short8*)&WT[(size_t)(nt * 16 + rt) * 128 + k0];
            gacc[nt] = __builtin_amdgcn_mfma_f32_16x16x32_bf16(
                av.v, bf, gacc[nt], 0, 0, 0);
        }
    }

    // node ids of the wave's 4 rows (held by lanes 0,16,32,48)
    int nrow[4];
#pragma unroll
    for (int r = 0; r < 4; r++) nrow[r] = __shfl(node, r << 4, 64);

    // valid output: qt==0 lanes hold cols rt(+16*nt), rows 0..3 in regs 0..3
    int rep = ((blockIdx.x << 2) + wave) & (NREP1 - 1);
#pragma unroll
    for (int nt = 0; nt < 8; nt++) {
        float b = bias[nt * 16 + rt];
        float csum = 0.f, csq = 0.f;
#pragma unroll
        for (int r = 0; r < 4; r++) {
            float v = gacc[nt][r] + b;
            if (qt == 0) C[(size_t)nrow[r] * 128 + nt * 16 + rt] = f2b(v);
            csum += v; csq += v * v;
        }
        if (qt == 0) {
            atomicAdd(&stats[(rep << 8) + nt * 16 + rt], csum);
            atomicAdd(&stats[(rep << 8) + 128 + nt * 16 + rt], csq);
        }
    }
}

// --------- GEMM2: LDS-staged WT + prefetched A (R7 proven form) -------------
__global__ __launch_bounds__(256) void k_gemm2(
    const ushort* __restrict__ A, const unsigned short* __restrict__ WT,
    const float* __restrict__ bias, ushort* __restrict__ C,
    const float* __restrict__ statsIn, const float* __restrict__ gamma,
    const float* __restrict__ beta, float* __restrict__ stats) {
    __shared__ ushort wlds[16384];       // 32 KB WT tile, XOR-swizzled
    __shared__ float lstat[256];
    __shared__ float s_sc[128], s_sh[128];
    int tid = threadIdx.x;

#pragma unroll
    for (int it = 0; it < 8; it++) {
        int i = tid * 8 + it * 2048;     // ushort index
        int row = i >> 7;
        short8 v = *(const short8*)&WT[i];
        *(short8*)((char*)wlds + ((i * 2) ^ ((row & 7) << 4))) = v;
    }

    if (tid < 128) {
        float s = 0.f, qq = 0.f;
#pragma unroll
        for (int r = 0; r < NREP1; r++) {
            s  += statsIn[r * 256 + tid];
            qq += statsIn[r * 256 + 128 + tid];
        }
        float m = s * (1.f / NNODES);
        float var = qq * (1.f / NNODES) - m * m;
        float sc = gamma[tid] * rsqrtf(var + BN_EPS);
        s_sc[tid] = sc;
        s_sh[tid] = beta[tid] - m * sc;
    }
    lstat[tid] = 0.f;

    int wave = tid >> 6;
    int lane = tid & 63;
    int q = lane >> 4;
    int l16 = lane & 15;
    int rowbase = blockIdx.x * 128 + wave * 32;

    short8 araw[2][4];
#pragma unroll
    for (int rt = 0; rt < 2; rt++) {
        int row = rowbase + rt * 16 + l16;
        if (row >= NNODES) row = NNODES - 1;
#pragma unroll
        for (int kc = 0; kc < 4; kc++)
            araw[rt][kc] = *(const short8*)&A[(size_t)row * 128 + kc * 32 + q * 8];
    }

    f32x4 acc[2][8];
#pragma unroll
    for (int rt = 0; rt < 2; rt++)
#pragma unroll
        for (int nt = 0; nt < 8; nt++) acc[rt][nt] = (f32x4){0.f, 0.f, 0.f, 0.f};

    __syncthreads();   // wlds + s_sc/s_sh ready

#pragma unroll
    for (int kc = 0; kc < 4; kc++) {
        int k0 = kc * 32 + q * 8;
        short8 bf[8];
#pragma unroll
        for (int nt = 0; nt < 8; nt++) {
            int row = nt * 16 + l16;
            bf[nt] = *(const short8*)(
                (char*)wlds + ((row * 256 + k0 * 2) ^ ((row & 7) << 4)));
        }

        float4 s0 = *(const float4*)&s_sc[k0];
        float4 s1 = *(const float4*)&s_sc[k0 + 4];
        float4 t0 = *(const float4*)&s_sh[k0];
        float4 t1 = *(const float4*)&s_sh[k0 + 4];
        float scl[8] = {s0.x, s0.y, s0.z, s0.w, s1.x, s1.y, s1.z, s1.w};
        float shf[8] = {t0.x, t0.y, t0.z, t0.w, t1.x, t1.y, t1.z, t1.w};
#pragma unroll
        for (int rt = 0; rt < 2; rt++) {
            union { short8 s; unsigned short u[8]; } in, cv;
            in.s = araw[rt][kc];
#pragma unroll
            for (int j = 0; j < 8; j++) {
                float f = fmaxf(b2f(in.u[j]) * scl[j] + shf[j], 0.f);
                cv.u[j] = f2b(f);
            }
#pragma unroll
            for (int nt = 0; nt < 8; nt++)
                acc[rt][nt] = __builtin_amdgcn_mfma_f32_16x16x32_bf16(
                    cv.s, bf[nt], acc[rt][nt], 0, 0, 0);
        }
    }

#pragma unroll
    for (int nt = 0; nt < 8; nt++) {
        float b = bias[nt * 16 + l16];
        float csum = 0.f, csq = 0.f;
#pragma unroll
        for (int rt = 0; rt < 2; rt++) {
            int rb = rowbase + rt * 16 + q * 4;
#pragma unroll
            for (int r = 0; r < 4; r++) {
                int row = rb + r;
                if (row < NNODES) {
                    float v = acc[rt][nt][r] + b;
                    C[(size_t)row * 128 + nt * 16 + l16] = f2b(v);
                    csum += v; csq += v * v;
                }
            }
        }
        csum += __shfl_xor(csum, 16, 64); csq += __shfl_xor(csq, 16, 64);
        csum += __shfl_xor(csum, 32, 64); csq += __shfl_xor(csq, 32, 64);
        if (q == 0) {
            atomicAdd(&lstat[nt * 16 + l16], csum);
            atomicAdd(&lstat[128 + nt * 16 + l16], csq);
        }
    }
    __syncthreads();
    atomicAdd(&stats[((blockIdx.x & (NREP2 - 1)) << 8) + tid], lstat[tid]);
}

// ---- resid: h += relu(BN2(t2b)); hb = bf16(h) ------------------------------
__global__ void k_resid(float* __restrict__ h, ushort* __restrict__ hb,
                        const ushort* __restrict__ t2b,
                        const float* __restrict__ statsIn,
                        const float* __restrict__ gamma, const float* __restrict__ beta) {
    __shared__ float s_sc[128], s_sh[128];
    int tid = threadIdx.x;
    if (tid < 128) {
        float s = 0.f, qq = 0.f;
#pragma unroll
        for (int r = 0; r < NREP2; r++) {
            s  += statsIn[r * 256 + tid];
            qq += statsIn[r * 256 + 128 + tid];
        }
        float m = s * (1.f / NNODES);
        float var = qq * (1.f / NNODES) - m * m;
        float sc = gamma[tid] * rsqrtf(var + BN_EPS);
        s_sc[tid] = sc;
        s_sh[tid] = beta[tid] - m * sc;
    }
    __syncthreads();
    int i = blockIdx.x * 256 + tid;
    int c4 = (i & 31) * 4;
    float4 sc = *(const float4*)&s_sc[c4];
    float4 sh = *(const float4*)&s_sh[c4];
    ushort4 t = ((const ushort4*)t2b)[i];
    float4 hv = ((float4*)h)[i];
    hv.x += fmaxf(b2f(t.x) * sc.x + sh.x, 0.f);
    hv.y += fmaxf(b2f(t.y) * sc.y + sh.y, 0.f);
    hv.z += fmaxf(b2f(t.z) * sc.z + sh.z, 0.f);
    hv.w += fmaxf(b2f(t.w) * sc.w + sh.w, 0.f);
    ((float4*)h)[i] = hv;
    ushort4 o;
    o.x = f2b(hv.x); o.y = f2b(hv.y); o.z = f2b(hv.z); o.w = f2b(hv.w);
    ((ushort4*)hb)[i] = o;
}

// ---------------- pooling (with count histogram) + projection ----------------
__global__ void k_pool(const float* __restrict__ h, const int* __restrict__ batch,
                       float* __restrict__ pooled, float* __restrict__ gcnt) {
    __shared__ float4 red[256];
    __shared__ int lcnt[NGRAPHS];
    int t = threadIdx.x;
    int d4 = t & 31, sub = t >> 5;
    int n0 = blockIdx.x * 128;
    if (n0 >= NNODES) return;
    int n1 = n0 + 128; if (n1 > NNODES) n1 = NNODES;
    if (t < NGRAPHS) lcnt[t] = 0;
    __syncthreads();
    if (t < n1 - n0) atomicAdd(&lcnt[batch[n0 + t]], 1);
    __syncthreads();
    if (t < NGRAPHS && lcnt[t]) atomicAdd(&gcnt[t], (float)lcnt[t]);

    int glo = batch[n0], ghi = batch[n1 - 1];
    for (int g = glo; g <= ghi; g++) {
        float4 acc = make_float4(0.f, 0.f, 0.f, 0.f);
        for (int r = n0 + sub; r < n1; r += 8) {
            if (batch[r] == g) {
                float4 v = ((const float4*)h)[(size_t)r * 32 + d4];
                acc.x += v.x; acc.y += v.y; acc.z += v.z; acc.w += v.w;
            }
        }
        red[t] = acc;
        __syncthreads();
        if (sub < 4) {
            float4 o = red[t + 128];
            red[t].x += o.x; red[t].y += o.y; red[t].z += o.z; red[t].w += o.w;
        }
        __syncthreads();
        if (sub < 2) {
            float4 o = red[t + 64];
            red[t].x += o.x; red[t].y += o.y; red[t].z += o.z; red[t].w += o.w;
        }
        __syncthreads();
        if (sub == 0) {
            float4 o = red[t + 32];
            float4 a = red[t];
            a.x += o.x; a.y += o.y; a.z += o.z; a.w += o.w;
            atomicAdd(&pooled[g * 128 + d4 * 4 + 0], a.x);
            atomicAdd(&pooled[g * 128 + d4 * 4 + 1], a.y);
            atomicAdd(&pooled[g * 128 + d4 * 4 + 2], a.z);
            atomicAdd(&pooled[g * 128 + d4 * 4 + 3], a.w);
        }
        __syncthreads();
    }
}

__global__ void k_proj(const float* __restrict__ pooled, const float* __restrict__ cnt,
                       const float* __restrict__ wp, const float* __restrict__ bp,
                       float* __restrict__ out) {
    __shared__ float prow[128];
    int g = blockIdx.x, c = threadIdx.x;
    if (c < 128) prow[c] = pooled[g * 128 + c] / fmaxf(cnt[g], 1.f);
    __syncthreads();
    float acc = bp[c];
    for (int k = 0; k < 128; k++) acc += prow[k] * wp[k * 256 + c];
    out[g * 256 + c] = acc;
}

extern "C" void kernel_launch(void* const* d_in, const int* in_sizes, int n_in,
                              void* d_out, int out_size, void* d_ws, size_t ws_size,
                              hipStream_t stream) {
    const float* x    = (const float*)d_in[0];
    const int*   eidx = (const int*)d_in[1];
    const int*   batch= (const int*)d_in[2];
    const float* w1   = (const float*)d_in[3];
    const float* b1   = (const float*)d_in[4];
    const float* g1   = (const float*)d_in[5];
    const float* be1  = (const float*)d_in[6];
    const float* w2   = (const float*)d_in[7];
    const float* b2   = (const float*)d_in[8];
    const float* gbn  = (const float*)d_in[9];
    const float* bbn  = (const float*)d_in[10];
    const float* wp   = (const float*)d_in[11];
    const float* bp   = (const float*)d_in[12];

    float* out  = (float*)d_out;
    float* gemb = out;                          // [64,256]
    float* h    = out + (size_t)NGRAPHS * OUTD; // node_emb lives in d_out

    char* w = (char*)d_ws;
    ushort* hb   = (ushort*)w; w += (size_t)NNODES * 128 * 2; // bf16 mirror of h
    ushort* t2b  = (ushort*)w; w += (size_t)NNODES * 128 * 2; // bf16 t2
    ushort* tb   = (ushort*)w; w += (size_t)NNODES * 128 * 2; // bf16 t
    int2*  off2  = (int2*)w;  w += (size_t)NNODES * 8;
    int*   adj   = (int*)w;   w += (size_t)NBUCK * BUCKCAP * 4;
    unsigned short* WT = (unsigned short*)w; w += (size_t)10 * 16384 * 2;
    int*   bcur  = (int*)w;   w += 256 * 4;
    // per layer: NREP1*256 (stats1) + NREP2*256 (stats2)
    float* statsAll = (float*)w; w += (size_t)NLAYERS * (NREP1 + NREP2) * 256 * 4;
    float* pooled= (float*)w; w += (size_t)NGRAPHS * HID * 4;
    float* gcnt  = (float*)w; w += NGRAPHS * 4;
    int*   dhist = (int*)w;   w += 1024 * 4;   // padded 64 bins (stride 16)
    int*   dcur  = (int*)w;   w += 1024 * 4;   // padded cursors
    int*   perm  = (int*)w;   w += (size_t)NNODES * 4;

    // packed edge buffer aliases tb (dead until layer loop)
    unsigned int* packed = (unsigned int*)tb;

    const int* srcv = eidx;
    const int* dstv = eidx + NEDGES;

    // h = x, hb = bf16(x), W transposes, bcur init (one launch)
    k_init<<<12500 + 640, 256, 0, stream>>>(x, h, hb, w1, w2, WT, bcur);

    // zero stats replicas + pooled + gcnt + dhist + dcur in one shot
    hipMemsetAsync(statsAll, 0,
                   ((size_t)NLAYERS * (NREP1 + NREP2) * 256 + NGRAPHS * HID + NGRAPHS
                    + 2048) * 4, stream);

    // CSR build + degree-sorted permutation
    k_fill1<<<FILL_BLOCKS, 256, 0, stream>>>(srcv, dstv, bcur, packed);
    k_fill2<<<NBUCK, 256, 0, stream>>>(packed, bcur, off2, adj, dhist);
    k_dscan<<<1, 64, 0, stream>>>(dhist, dcur);
    k_dscat<<<(NNODES + 255) / 256, 256, 0, stream>>>(off2, dcur, perm);

    for (int i = 0; i < NLAYERS; i++) {
        float* st1 = statsAll + (size_t)i * (NREP1 + NREP2) * 256;
        float* st2 = st1 + (size_t)NREP1 * 256;
        k_ag1<<<AG1B, 256, 0, stream>>>(
            hb, off2, adj, perm, WT + (size_t)i * 16384, b1 + i * HID, tb, st1);
        k_gemm2<<<(NNODES + 127) / 128, 256, 0, stream>>>(
            tb, WT + (size_t)(5 + i) * 16384, b2 + i * HID, t2b,
            st1, g1 + i * HID, be1 + i * HID, st2);
        k_resid<<<NNODES * 128 / 4 / 256, 256, 0, stream>>>(
            h, hb, t2b, st2, gbn + i * HID, bbn + i * HID);
    }

    // pooling (+counts) + projection
    k_pool<<<(NNODES + 127) / 128, 256, 0, stream>>>(h, batch, pooled, gcnt);
    k_proj<<<NGRAPHS, 256, 0, stream>>>(pooled, gcnt, wp, bp, gemb);
}

// Round 10
// 889.538 us; speedup vs baseline: 1.3855x; 1.3855x over previous
//
#include <hip/hip_runtime.h>

#define NNODES 100000
#define NEDGES 1600000
#define NGRAPHS 64
#define HID 128
#define OUTD 256
#define NLAYERS 5
#define BN_EPS 1e-5f
#define NBUCK 196          // ceil(NNODES/512)
#define BUCKCAP 9216       // avg 8192 edges/bucket + 11 sigma
#define FILL_BLOCKS 391    // ceil(NEDGES/4096)
#define NREP1 64           // stats replicas for fused agg+gemm1 (6250 blocks)
#define NREP2 8            // stats replicas for gemm2 (782 blocks)
#define AG1B 6250          // NNODES/16 fused agg+gemm1 blocks

typedef __attribute__((ext_vector_type(8))) short short8;
typedef __attribute__((ext_vector_type(4))) float f32x4;

__device__ inline unsigned short f2b(float f) {
    union { float f; unsigned int u; } a; a.f = f;
    unsigned int u = a.u;
    return (unsigned short)((u + 0x7FFF + ((u >> 16) & 1)) >> 16);  // RNE
}
__device__ inline float b2f(unsigned short b) {
    union { unsigned int u; float f; } a; a.u = ((unsigned int)b) << 16;
    return a.f;
}

union U8 { short8 v; unsigned short u[8]; };

// -------- init: h = x (fp32), hb = bf16(x) row-major; W^T; bcur -------------
__global__ void k_init(const float* __restrict__ x, float* __restrict__ h,
                       ushort* __restrict__ hb,
                       const float* __restrict__ w1, const float* __restrict__ w2,
                       unsigned short* __restrict__ WT, int* __restrict__ bcur) {
    int b = blockIdx.x;
    if (b < 12500) {
        int i = b * 256 + threadIdx.x;  // float4 index
        float4 v = ((const float4*)x)[i];
        ((float4*)h)[i] = v;
        ushort4 o;
        o.x = f2b(v.x); o.y = f2b(v.y); o.z = f2b(v.z); o.w = f2b(v.w);
        ((ushort4*)hb)[i] = o;
    } else {
        int t = (b - 12500) * 256 + threadIdx.x;
        int mat = t >> 14;
        int rem = t & 16383;
        int k = rem >> 7, n = rem & 127;
        const float* src = (mat < 5) ? &w1[(size_t)mat * 16384]
                                     : &w2[(size_t)(mat - 5) * 16384];
        WT[(size_t)mat * 16384 + n * 128 + k] = f2b(src[k * 128 + n]);
        if (b == 12500 && threadIdx.x < NBUCK)
            bcur[threadIdx.x] = threadIdx.x * BUCKCAP;
    }
}

// ---------------- CSR build (bucketed, no global per-node histogram) --------
__global__ __launch_bounds__(256) void k_fill1(
    const int* __restrict__ srcv, const int* __restrict__ dstv,
    int* __restrict__ bcur, unsigned int* __restrict__ packed) {
    __shared__ int hist[NBUCK];
    __shared__ int base[NBUCK];
    int tid = threadIdx.x;
    int e0 = blockIdx.x * 4096;
    for (int i = tid; i < NBUCK; i += 256) hist[i] = 0;
    __syncthreads();
#pragma unroll
    for (int i = 0; i < 16; i++) {
        int e = e0 + i * 256 + tid;
        if (e < NEDGES) atomicAdd(&hist[dstv[e] >> 9], 1);
    }
    __syncthreads();
    for (int i = tid; i < NBUCK; i += 256) {
        int c = hist[i];
        base[i] = c ? atomicAdd(&bcur[i], c) : 0;
        hist[i] = 0;
    }
    __syncthreads();
#pragma unroll
    for (int i = 0; i < 16; i++) {
        int e = e0 + i * 256 + tid;
        if (e < NEDGES) {
            int d = dstv[e];
            int b = d >> 9;
            int r = atomicAdd(&hist[b], 1);
            packed[base[b] + r] = ((unsigned int)srcv[e] << 9) | (unsigned int)(d & 511);
        }
    }
}

// Phase 2 + degree histogram (padded bins: dhist[d*16])
__global__ __launch_bounds__(256) void k_fill2(
    const unsigned int* __restrict__ packed, const int* __restrict__ bcur,
    int2* __restrict__ off2, int* __restrict__ adj, int* __restrict__ dhist) {
    __shared__ int deg[512];
    __shared__ int cur[512];
    __shared__ int dh[64];
    int tid = threadIdx.x;
    int b = blockIdx.x;
    int base = b * BUCKCAP;
    int cnt = bcur[b] - base;
    deg[tid] = 0; deg[tid + 256] = 0;
    if (tid < 64) dh[tid] = 0;
    __syncthreads();
    for (int i = tid; i < cnt; i += 256)
        atomicAdd(&deg[packed[base + i] & 511], 1);
    __syncthreads();
    cur[tid] = deg[tid]; cur[tid + 256] = deg[tid + 256];
    __syncthreads();
    for (int o = 1; o < 512; o <<= 1) {
        int u0 = (tid >= o) ? cur[tid - o] : 0;
        int u1 = (tid + 256 >= o) ? cur[tid + 256 - o] : 0;
        __syncthreads();
        cur[tid] += u0; cur[tid + 256] += u1;
        __syncthreads();
    }
    int nbase = b * 512;
#pragma unroll
    for (int i = 0; i < 2; i++) {
        int t = tid + i * 256;
        int st = base + cur[t] - deg[t];   // exclusive scan + bucket base
        int n = nbase + t;
        if (n < NNODES) {
            off2[n] = make_int2(st, st + deg[t]);
            int d = deg[t]; if (d > 63) d = 63;
            atomicAdd(&dh[d], 1);
        }
    }
    __syncthreads();
    if (tid < 64 && dh[tid]) atomicAdd(&dhist[tid * 16], dh[tid]);
#pragma unroll
    for (int i = 0; i < 2; i++) {
        int t = tid + i * 256;
        cur[t] = base + cur[t] - deg[t];   // absolute cursors
    }
    __syncthreads();
    for (int i = tid; i < cnt; i += 256) {
        unsigned int p = packed[base + i];
        int r = atomicAdd(&cur[p & 511], 1);
        adj[r] = (int)(p >> 9);
    }
}

// exclusive prefix, DESCENDING degree (LPT: heavy blocks launch first)
__global__ void k_dscan(const int* __restrict__ dhist, int* __restrict__ dcur) {
    if (threadIdx.x == 0) {
        int s = 0;
        for (int i = 63; i >= 0; i--) { int c = dhist[i * 16]; dcur[i * 16] = s; s += c; }
    }
}

// scatter nodes into degree-sorted perm + pre-permuted off2p
__global__ __launch_bounds__(256) void k_dscat(
    const int2* __restrict__ off2, int* __restrict__ dcur,
    int* __restrict__ perm, int2* __restrict__ off2p) {
    __shared__ int h[64], base[64];
    int tid = threadIdx.x;
    int n = blockIdx.x * 256 + tid;
    if (tid < 64) h[tid] = 0;
    __syncthreads();
    int d = 0; int2 oo = make_int2(0, 0);
    if (n < NNODES) {
        oo = off2[n];
        d = oo.y - oo.x; if (d > 63) d = 63;
        atomicAdd(&h[d], 1);
    }
    __syncthreads();
    if (tid < 64) { int c = h[tid]; base[tid] = c ? atomicAdd(&dcur[tid * 16], c) : 0; h[tid] = 0; }
    __syncthreads();
    if (n < NNODES) {
        int r = atomicAdd(&h[d], 1);
        int pos = base[d] + r;
        perm[pos] = n;
        off2p[pos] = oo;
    }
}

// ---- fused agg+GEMM1, degree-sorted (LPT) blocks, R8-proven structure ------
__global__ __launch_bounds__(256) void k_ag1(
    const ushort* __restrict__ hb, const int2* __restrict__ off2p,
    const int* __restrict__ adj, const int* __restrict__ perm,
    const unsigned short* __restrict__ WT,
    const float* __restrict__ bias, ushort* __restrict__ C,
    float* __restrict__ stats) {
    __shared__ ushort zt[16 * 128];     // 4 KB, swizzled: byte ^= (row&7)<<4
    __shared__ float lstat[256];
    int tid = threadIdx.x;
    int n = tid >> 4;                   // local row 0..15
    int c = tid & 15;                   // 16B chunk of the 256B row
    int idx = blockIdx.x * 16 + n;
    int node = perm[idx];               // coalesced, independent of off2p read
    int2 oo = off2p[idx];               // coalesced, no dependent chain
    const short8* hb8 = (const short8*)hb;

    U8 sv; sv.v = hb8[(size_t)node * 16 + c];
    float acc[8];
#pragma unroll
    for (int k = 0; k < 8; k++) acc[k] = b2f(sv.u[k]);

    int e = oo.x, e1 = oo.y;
    for (; e + 8 <= e1; e += 8) {
        int s[8];
#pragma unroll
        for (int j = 0; j < 8; j++) s[j] = adj[e + j];
        U8 u[8];
#pragma unroll
        for (int j = 0; j < 8; j++) u[j].v = hb8[(size_t)s[j] * 16 + c];
#pragma unroll
        for (int j = 0; j < 8; j++)
#pragma unroll
            for (int k = 0; k < 8; k++) acc[k] += b2f(u[j].u[k]);
    }
    for (; e + 4 <= e1; e += 4) {
        int s0 = adj[e], s1 = adj[e + 1], s2 = adj[e + 2], s3 = adj[e + 3];
        U8 u0, u1, u2, u3;
        u0.v = hb8[(size_t)s0 * 16 + c];
        u1.v = hb8[(size_t)s1 * 16 + c];
        u2.v = hb8[(size_t)s2 * 16 + c];
        u3.v = hb8[(size_t)s3 * 16 + c];
#pragma unroll
        for (int k = 0; k < 8; k++)
            acc[k] += (b2f(u0.u[k]) + b2f(u1.u[k])) + (b2f(u2.u[k]) + b2f(u3.u[k]));
    }
    for (; e < e1; e++) {
        int s = adj[e];
        U8 u; u.v = hb8[(size_t)s * 16 + c];
#pragma unroll
        for (int k = 0; k < 8; k++) acc[k] += b2f(u.u[k]);
    }

    U8 o;
#pragma unroll
    for (int k = 0; k < 8; k++) o.u[k] = f2b(acc[k]);
    *(short8*)((char*)zt + ((n * 256 + c * 16) ^ ((n & 7) << 4))) = o.v;
    __syncthreads();

    // ---- GEMM epilogue: wave w -> output cols 32w..32w+31 for all 16 rows --
    int wave = tid >> 6;
    int lane = tid & 63;
    int q = lane >> 4;
    int l16 = lane & 15;

    f32x4 gacc[2];
    gacc[0] = (f32x4){0.f, 0.f, 0.f, 0.f};
    gacc[1] = (f32x4){0.f, 0.f, 0.f, 0.f};

#pragma unroll
    for (int kc = 0; kc < 4; kc++) {
        int k0 = kc * 32 + q * 8;
        int ch = kc * 4 + q;
        short8 av = *(const short8*)(
            (char*)zt + ((l16 * 256 + ch * 16) ^ ((l16 & 7) << 4)));
#pragma unroll
        for (int nt = 0; nt < 2; nt++) {
            int col0 = (wave * 2 + nt) * 16;
            short8 bf = *(const short8*)&WT[(size_t)(col0 + l16) * 128 + k0];
            gacc[nt] = __builtin_amdgcn_mfma_f32_16x16x32_bf16(
                av, bf, gacc[nt], 0, 0, 0);
        }
    }

    int rowbase = blockIdx.x * 16;
    int prow[4];
#pragma unroll
    for (int r = 0; r < 4; r++) prow[r] = perm[rowbase + q * 4 + r];
#pragma unroll
    for (int nt = 0; nt < 2; nt++) {
        int col = (wave * 2 + nt) * 16 + l16;
        float b = bias[col];
        float csum = 0.f, csq = 0.f;
#pragma unroll
        for (int r = 0; r < 4; r++) {
            float v = gacc[nt][r] + b;
            C[(size_t)prow[r] * 128 + col] = f2b(v);
            csum += v; csq += v * v;
        }
        csum += __shfl_xor(csum, 16, 64); csq += __shfl_xor(csq, 16, 64);
        csum += __shfl_xor(csum, 32, 64); csq += __shfl_xor(csq, 32, 64);
        if (q == 0) { lstat[col] = csum; lstat[128 + col] = csq; }
    }
    __syncthreads();
    atomicAdd(&stats[((blockIdx.x & (NREP1 - 1)) << 8) + tid], lstat[tid]);
}

// --------- GEMM2: LDS-staged WT + prefetched A (R7 proven form) -------------
__global__ __launch_bounds__(256) void k_gemm2(
    const ushort* __restrict__ A, const unsigned short* __restrict__ WT,
    const float* __restrict__ bias, ushort* __restrict__ C,
    const float* __restrict__ statsIn, const float* __restrict__ gamma,
    const float* __restrict__ beta, float* __restrict__ stats) {
    __shared__ ushort wlds[16384];       // 32 KB WT tile, XOR-swizzled
    __shared__ float lstat[256];
    __shared__ float s_sc[128], s_sh[128];
    int tid = threadIdx.x;

#pragma unroll
    for (int it = 0; it < 8; it++) {
        int i = tid * 8 + it * 2048;     // ushort index
        int row = i >> 7;
        short8 v = *(const short8*)&WT[i];
        *(short8*)((char*)wlds + ((i * 2) ^ ((row & 7) << 4))) = v;
    }

    if (tid < 128) {
        float s = 0.f, qq = 0.f;
#pragma unroll
        for (int r = 0; r < NREP1; r++) {
            s  += statsIn[r * 256 + tid];
            qq += statsIn[r * 256 + 128 + tid];
        }
        float m = s * (1.f / NNODES);
        float var = qq * (1.f / NNODES) - m * m;
        float sc = gamma[tid] * rsqrtf(var + BN_EPS);
        s_sc[tid] = sc;
        s_sh[tid] = beta[tid] - m * sc;
    }
    lstat[tid] = 0.f;

    int wave = tid >> 6;
    int lane = tid & 63;
    int q = lane >> 4;
    int l16 = lane & 15;
    int rowbase = blockIdx.x * 128 + wave * 32;

    short8 araw[2][4];
#pragma unroll
    for (int rt = 0; rt < 2; rt++) {
        int row = rowbase + rt * 16 + l16;
        if (row >= NNODES) row = NNODES - 1;
#pragma unroll
        for (int kc = 0; kc < 4; kc++)
            araw[rt][kc] = *(const short8*)&A[(size_t)row * 128 + kc * 32 + q * 8];
    }

    f32x4 acc[2][8];
#pragma unroll
    for (int rt = 0; rt < 2; rt++)
#pragma unroll
        for (int nt = 0; nt < 8; nt++) acc[rt][nt] = (f32x4){0.f, 0.f, 0.f, 0.f};

    __syncthreads();   // wlds + s_sc/s_sh ready

#pragma unroll
    for (int kc = 0; kc < 4; kc++) {
        int k0 = kc * 32 + q * 8;
        short8 bf[8];
#pragma unroll
        for (int nt = 0; nt < 8; nt++) {
            int row = nt * 16 + l16;
            bf[nt] = *(const short8*)(
                (char*)wlds + ((row * 256 + k0 * 2) ^ ((row & 7) << 4)));
        }

        float4 s0 = *(const float4*)&s_sc[k0];
        float4 s1 = *(const float4*)&s_sc[k0 + 4];
        float4 t0 = *(const float4*)&s_sh[k0];
        float4 t1 = *(const float4*)&s_sh[k0 + 4];
        float scl[8] = {s0.x, s0.y, s0.z, s0.w, s1.x, s1.y, s1.z, s1.w};
        float shf[8] = {t0.x, t0.y, t0.z, t0.w, t1.x, t1.y, t1.z, t1.w};
#pragma unroll
        for (int rt = 0; rt < 2; rt++) {
            union { short8 s; unsigned short u[8]; } in, cv;
            in.s = araw[rt][kc];
#pragma unroll
            for (int j = 0; j < 8; j++) {
                float f = fmaxf(b2f(in.u[j]) * scl[j] + shf[j], 0.f);
                cv.u[j] = f2b(f);
            }
#pragma unroll
            for (int nt = 0; nt < 8; nt++)
                acc[rt][nt] = __builtin_amdgcn_mfma_f32_16x16x32_bf16(
                    cv.s, bf[nt], acc[rt][nt], 0, 0, 0);
        }
    }

#pragma unroll
    for (int nt = 0; nt < 8; nt++) {
        float b = bias[nt * 16 + l16];
        float csum = 0.f, csq = 0.f;
#pragma unroll
        for (int rt = 0; rt < 2; rt++) {
            int rb = rowbase + rt * 16 + q * 4;
#pragma unroll
            for (int r = 0; r < 4; r++) {
                int row = rb + r;
                if (row < NNODES) {
                    float v = acc[rt][nt][r] + b;
                    C[(size_t)row * 128 + nt * 16 + l16] = f2b(v);
                    csum += v; csq += v * v;
                }
            }
        }
        csum += __shfl_xor(csum, 16, 64); csq += __shfl_xor(csq, 16, 64);
        csum += __shfl_xor(csum, 32, 64); csq += __shfl_xor(csq, 32, 64);
        if (q == 0) {
            atomicAdd(&lstat[nt * 16 + l16], csum);
            atomicAdd(&lstat[128 + nt * 16 + l16], csq);
        }
    }
    __syncthreads();
    atomicAdd(&stats[((blockIdx.x & (NREP2 - 1)) << 8) + tid], lstat[tid]);
}

// ---- resid: h += relu(BN2(t2b)); hb = bf16(h) ------------------------------
__global__ void k_resid(float* __restrict__ h, ushort* __restrict__ hb,
                        const ushort* __restrict__ t2b,
                        const float* __restrict__ statsIn,
                        const float* __restrict__ gamma, const float* __restrict__ beta) {
    __shared__ float s_sc[128], s_sh[128];
    int tid = threadIdx.x;
    if (tid < 128) {
        float s = 0.f, qq = 0.f;
#pragma unroll
        for (int r = 0; r < NREP2; r++) {
            s  += statsIn[r * 256 + tid];
            qq += statsIn[r * 256 + 128 + tid];
        }
        float m = s * (1.f / NNODES);
        float var = qq * (1.f / NNODES) - m * m;
        float sc = gamma[tid] * rsqrtf(var + BN_EPS);
        s_sc[tid] = sc;
        s_sh[tid] = beta[tid] - m * sc;
    }
    __syncthreads();
    int i = blockIdx.x * 256 + tid;
    int c4 = (i & 31) * 4;
    float4 sc = *(const float4*)&s_sc[c4];
    float4 sh = *(const float4*)&s_sh[c4];
    ushort4 t = ((const ushort4*)t2b)[i];
    float4 hv = ((float4*)h)[i];
    hv.x += fmaxf(b2f(t.x) * sc.x + sh.x, 0.f);
    hv.y += fmaxf(b2f(t.y) * sc.y + sh.y, 0.f);
    hv.z += fmaxf(b2f(t.z) * sc.z + sh.z, 0.f);
    hv.w += fmaxf(b2f(t.w) * sc.w + sh.w, 0.f);
    ((float4*)h)[i] = hv;
    ushort4 o;
    o.x = f2b(hv.x); o.y = f2b(hv.y); o.z = f2b(hv.z); o.w = f2b(hv.w);
    ((ushort4*)hb)[i] = o;
}

// ---------------- pooling (with count histogram) + projection ----------------
__global__ void k_pool(const float* __restrict__ h, const int* __restrict__ batch,
                       float* __restrict__ pooled, float* __restrict__ gcnt) {
    __shared__ float4 red[256];
    __shared__ int lcnt[NGRAPHS];
    int t = threadIdx.x;
    int d4 = t & 31, sub = t >> 5;
    int n0 = blockIdx.x * 128;
    if (n0 >= NNODES) return;
    int n1 = n0 + 128; if (n1 > NNODES) n1 = NNODES;
    if (t < NGRAPHS) lcnt[t] = 0;
    __syncthreads();
    if (t < n1 - n0) atomicAdd(&lcnt[batch[n0 + t]], 1);
    __syncthreads();
    if (t < NGRAPHS && lcnt[t]) atomicAdd(&gcnt[t], (float)lcnt[t]);

    int glo = batch[n0], ghi = batch[n1 - 1];
    for (int g = glo; g <= ghi; g++) {
        float4 acc = make_float4(0.f, 0.f, 0.f, 0.f);
        for (int r = n0 + sub; r < n1; r += 8) {
            if (batch[r] == g) {
                float4 v = ((const float4*)h)[(size_t)r * 32 + d4];
                acc.x += v.x; acc.y += v.y; acc.z += v.z; acc.w += v.w;
            }
        }
        red[t] = acc;
        __syncthreads();
        if (sub < 4) {
            float4 o = red[t + 128];
            red[t].x += o.x; red[t].y += o.y; red[t].z += o.z; red[t].w += o.w;
        }
        __syncthreads();
        if (sub < 2) {
            float4 o = red[t + 64];
            red[t].x += o.x; red[t].y += o.y; red[t].z += o.z; red[t].w += o.w;
        }
        __syncthreads();
        if (sub == 0) {
            float4 o = red[t + 32];
            float4 a = red[t];
            a.x += o.x; a.y += o.y; a.z += o.z; a.w += o.w;
            atomicAdd(&pooled[g * 128 + d4 * 4 + 0], a.x);
            atomicAdd(&pooled[g * 128 + d4 * 4 + 1], a.y);
            atomicAdd(&pooled[g * 128 + d4 * 4 + 2], a.z);
            atomicAdd(&pooled[g * 128 + d4 * 4 + 3], a.w);
        }
        __syncthreads();
    }
}

__global__ void k_proj(const float* __restrict__ pooled, const float* __restrict__ cnt,
                       const float* __restrict__ wp, const float* __restrict__ bp,
                       float* __restrict__ out) {
    __shared__ float prow[128];
    int g = blockIdx.x, c = threadIdx.x;
    if (c < 128) prow[c] = pooled[g * 128 + c] / fmaxf(cnt[g], 1.f);
    __syncthreads();
    float acc = bp[c];
    for (int k = 0; k < 128; k++) acc += prow[k] * wp[k * 256 + c];
    out[g * 256 + c] = acc;
}

extern "C" void kernel_launch(void* const* d_in, const int* in_sizes, int n_in,
                              void* d_out, int out_size, void* d_ws, size_t ws_size,
                              hipStream_t stream) {
    const float* x    = (const float*)d_in[0];
    const int*   eidx = (const int*)d_in[1];
    const int*   batch= (const int*)d_in[2];
    const float* w1   = (const float*)d_in[3];
    const float* b1   = (const float*)d_in[4];
    const float* g1   = (const float*)d_in[5];
    const float* be1  = (const float*)d_in[6];
    const float* w2   = (const float*)d_in[7];
    const float* b2   = (const float*)d_in[8];
    const float* gbn  = (const float*)d_in[9];
    const float* bbn  = (const float*)d_in[10];
    const float* wp   = (const float*)d_in[11];
    const float* bp   = (const float*)d_in[12];

    float* out  = (float*)d_out;
    float* gemb = out;                          // [64,256]
    float* h    = out + (size_t)NGRAPHS * OUTD; // node_emb lives in d_out

    char* w = (char*)d_ws;
    ushort* hb   = (ushort*)w; w += (size_t)NNODES * 128 * 2; // bf16 mirror of h
    ushort* t2b  = (ushort*)w; w += (size_t)NNODES * 128 * 2; // bf16 t2
    ushort* tb   = (ushort*)w; w += (size_t)NNODES * 128 * 2; // bf16 t
    int2*  off2  = (int2*)w;  w += (size_t)NNODES * 8;
    int*   adj   = (int*)w;   w += (size_t)NBUCK * BUCKCAP * 4;
    unsigned short* WT = (unsigned short*)w; w += (size_t)10 * 16384 * 2;
    int*   bcur  = (int*)w;   w += 256 * 4;
    // per layer: NREP1*256 (stats1) + NREP2*256 (stats2)
    float* statsAll = (float*)w; w += (size_t)NLAYERS * (NREP1 + NREP2) * 256 * 4;
    float* pooled= (float*)w; w += (size_t)NGRAPHS * HID * 4;
    float* gcnt  = (float*)w; w += NGRAPHS * 4;
    int*   dhist = (int*)w;   w += 1024 * 4;   // padded 64 bins (stride 16)
    int*   dcur  = (int*)w;   w += 1024 * 4;   // padded cursors
    int*   perm  = (int*)w;   w += (size_t)NNODES * 4;
    int2*  off2p = (int2*)w;  w += (size_t)NNODES * 8;

    // packed edge buffer aliases tb (dead until layer loop)
    unsigned int* packed = (unsigned int*)tb;

    const int* srcv = eidx;
    const int* dstv = eidx + NEDGES;

    // h = x, hb = bf16(x), W transposes, bcur init (one launch)
    k_init<<<12500 + 640, 256, 0, stream>>>(x, h, hb, w1, w2, WT, bcur);

    // zero stats replicas + pooled + gcnt + dhist + dcur in one shot
    hipMemsetAsync(statsAll, 0,
                   ((size_t)NLAYERS * (NREP1 + NREP2) * 256 + NGRAPHS * HID + NGRAPHS
                    + 2048) * 4, stream);

    // CSR build + degree-sorted (descending, LPT) permutation
    k_fill1<<<FILL_BLOCKS, 256, 0, stream>>>(srcv, dstv, bcur, packed);
    k_fill2<<<NBUCK, 256, 0, stream>>>(packed, bcur, off2, adj, dhist);
    k_dscan<<<1, 64, 0, stream>>>(dhist, dcur);
    k_dscat<<<(NNODES + 255) / 256, 256, 0, stream>>>(off2, dcur, perm, off2p);

    for (int i = 0; i < NLAYERS; i++) {
        float* st1 = statsAll + (size_t)i * (NREP1 + NREP2) * 256;
        float* st2 = st1 + (size_t)NREP1 * 256;
        k_ag1<<<AG1B, 256, 0, stream>>>(
            hb, off2p, adj, perm, WT + (size_t)i * 16384, b1 + i * HID, tb, st1);
        k_gemm2<<<(NNODES + 127) / 128, 256, 0, stream>>>(
            tb, WT + (size_t)(5 + i) * 16384, b2 + i * HID, t2b,
            st1, g1 + i * HID, be1 + i * HID, st2);
        k_resid<<<NNODES * 128 / 4 / 256, 256, 0, stream>>>(
            h, hb, t2b, st2, gbn + i * HID, bbn + i * HID);
    }

    // pooling (+counts) + projection
    k_pool<<<(NNODES + 127) / 128, 256, 0, stream>>>(h, batch, pooled, gcnt);
    k_proj<<<NGRAPHS, 256, 0, stream>>>(pooled, gcnt, wp, bp, gemb);
}

// Round 11
// 858.643 us; speedup vs baseline: 1.4353x; 1.0360x over previous
//
#include <hip/hip_runtime.h>

#define NNODES 100000
#define NEDGES 1600000
#define NGRAPHS 64
#define HID 128
#define OUTD 256
#define NLAYERS 5
#define BN_EPS 1e-5f
#define NBUCK 196          // ceil(NNODES/512)
#define BUCKCAP 9216       // avg 8192 edges/bucket + 11 sigma
#define FILL_BLOCKS 391    // ceil(NEDGES/4096)
#define NREP1 64           // stats replicas for fused agg+gemm1 (6250 blocks)
#define NREP2 16           // stats replicas for gemm2 (1563 blocks)
#define AG1B 6250          // NNODES/16 fused agg+gemm1 blocks
#define G2B 1563           // ceil(NNODES/64) gemm2 blocks

typedef __attribute__((ext_vector_type(8))) short short8;
typedef __attribute__((ext_vector_type(4))) float f32x4;

__device__ inline unsigned short f2b(float f) {
    union { float f; unsigned int u; } a; a.f = f;
    unsigned int u = a.u;
    return (unsigned short)((u + 0x7FFF + ((u >> 16) & 1)) >> 16);  // RNE
}
__device__ inline float b2f(unsigned short b) {
    union { unsigned int u; float f; } a; a.u = ((unsigned int)b) << 16;
    return a.f;
}

union U8 { short8 v; unsigned short u[8]; };

// -------- init: h = x (fp32), hb = bf16(x) row-major; W^T; bcur -------------
__global__ void k_init(const float* __restrict__ x, float* __restrict__ h,
                       ushort* __restrict__ hb,
                       const float* __restrict__ w1, const float* __restrict__ w2,
                       unsigned short* __restrict__ WT, int* __restrict__ bcur) {
    int b = blockIdx.x;
    if (b < 12500) {
        int i = b * 256 + threadIdx.x;  // float4 index
        float4 v = ((const float4*)x)[i];
        ((float4*)h)[i] = v;
        ushort4 o;
        o.x = f2b(v.x); o.y = f2b(v.y); o.z = f2b(v.z); o.w = f2b(v.w);
        ((ushort4*)hb)[i] = o;
    } else {
        int t = (b - 12500) * 256 + threadIdx.x;
        int mat = t >> 14;
        int rem = t & 16383;
        int k = rem >> 7, n = rem & 127;
        const float* src = (mat < 5) ? &w1[(size_t)mat * 16384]
                                     : &w2[(size_t)(mat - 5) * 16384];
        WT[(size_t)mat * 16384 + n * 128 + k] = f2b(src[k * 128 + n]);
        if (b == 12500 && threadIdx.x < NBUCK)
            bcur[threadIdx.x] = threadIdx.x * BUCKCAP;
    }
}

// ---------------- CSR build (bucketed, no global per-node histogram) --------
__global__ __launch_bounds__(256) void k_fill1(
    const int* __restrict__ srcv, const int* __restrict__ dstv,
    int* __restrict__ bcur, unsigned int* __restrict__ packed) {
    __shared__ int hist[NBUCK];
    __shared__ int base[NBUCK];
    int tid = threadIdx.x;
    int e0 = blockIdx.x * 4096;
    for (int i = tid; i < NBUCK; i += 256) hist[i] = 0;
    __syncthreads();
#pragma unroll
    for (int i = 0; i < 16; i++) {
        int e = e0 + i * 256 + tid;
        if (e < NEDGES) atomicAdd(&hist[dstv[e] >> 9], 1);
    }
    __syncthreads();
    for (int i = tid; i < NBUCK; i += 256) {
        int c = hist[i];
        base[i] = c ? atomicAdd(&bcur[i], c) : 0;
        hist[i] = 0;
    }
    __syncthreads();
#pragma unroll
    for (int i = 0; i < 16; i++) {
        int e = e0 + i * 256 + tid;
        if (e < NEDGES) {
            int d = dstv[e];
            int b = d >> 9;
            int r = atomicAdd(&hist[b], 1);
            packed[base[b] + r] = ((unsigned int)srcv[e] << 9) | (unsigned int)(d & 511);
        }
    }
}

// Phase 2 + degree histogram (padded bins: dhist[d*16])
__global__ __launch_bounds__(256) void k_fill2(
    const unsigned int* __restrict__ packed, const int* __restrict__ bcur,
    int2* __restrict__ off2, int* __restrict__ adj, int* __restrict__ dhist) {
    __shared__ int deg[512];
    __shared__ int cur[512];
    __shared__ int dh[64];
    int tid = threadIdx.x;
    int b = blockIdx.x;
    int base = b * BUCKCAP;
    int cnt = bcur[b] - base;
    deg[tid] = 0; deg[tid + 256] = 0;
    if (tid < 64) dh[tid] = 0;
    __syncthreads();
    for (int i = tid; i < cnt; i += 256)
        atomicAdd(&deg[packed[base + i] & 511], 1);
    __syncthreads();
    cur[tid] = deg[tid]; cur[tid + 256] = deg[tid + 256];
    __syncthreads();
    for (int o = 1; o < 512; o <<= 1) {
        int u0 = (tid >= o) ? cur[tid - o] : 0;
        int u1 = (tid + 256 >= o) ? cur[tid + 256 - o] : 0;
        __syncthreads();
        cur[tid] += u0; cur[tid + 256] += u1;
        __syncthreads();
    }
    int nbase = b * 512;
#pragma unroll
    for (int i = 0; i < 2; i++) {
        int t = tid + i * 256;
        int st = base + cur[t] - deg[t];   // exclusive scan + bucket base
        int n = nbase + t;
        if (n < NNODES) {
            off2[n] = make_int2(st, st + deg[t]);
            int d = deg[t]; if (d > 63) d = 63;
            atomicAdd(&dh[d], 1);
        }
    }
    __syncthreads();
    if (tid < 64 && dh[tid]) atomicAdd(&dhist[tid * 16], dh[tid]);
#pragma unroll
    for (int i = 0; i < 2; i++) {
        int t = tid + i * 256;
        cur[t] = base + cur[t] - deg[t];   // absolute cursors
    }
    __syncthreads();
    for (int i = tid; i < cnt; i += 256) {
        unsigned int p = packed[base + i];
        int r = atomicAdd(&cur[p & 511], 1);
        adj[r] = (int)(p >> 9);
    }
}

// exclusive prefix, ascending degree (R8-measured-better ordering)
__global__ void k_dscan(const int* __restrict__ dhist, int* __restrict__ dcur) {
    if (threadIdx.x == 0) {
        int s = 0;
        for (int i = 0; i < 64; i++) { int c = dhist[i * 16]; dcur[i * 16] = s; s += c; }
    }
}

// scatter nodes into degree-sorted perm + pre-permuted off2p
__global__ __launch_bounds__(256) void k_dscat(
    const int2* __restrict__ off2, int* __restrict__ dcur,
    int* __restrict__ perm, int2* __restrict__ off2p) {
    __shared__ int h[64], base[64];
    int tid = threadIdx.x;
    int n = blockIdx.x * 256 + tid;
    if (tid < 64) h[tid] = 0;
    __syncthreads();
    int d = 0; int2 oo = make_int2(0, 0);
    if (n < NNODES) {
        oo = off2[n];
        d = oo.y - oo.x; if (d > 63) d = 63;
        atomicAdd(&h[d], 1);
    }
    __syncthreads();
    if (tid < 64) { int c = h[tid]; base[tid] = c ? atomicAdd(&dcur[tid * 16], c) : 0; h[tid] = 0; }
    __syncthreads();
    if (n < NNODES) {
        int r = atomicAdd(&h[d], 1);
        int pos = base[d] + r;
        perm[pos] = n;
        off2p[pos] = oo;
    }
}

// ---- fused agg+GEMM1, degree-sorted blocks (R8-proven structure) -----------
__global__ __launch_bounds__(256) void k_ag1(
    const ushort* __restrict__ hb, const int2* __restrict__ off2p,
    const int* __restrict__ adj, const int* __restrict__ perm,
    const unsigned short* __restrict__ WT,
    const float* __restrict__ bias, ushort* __restrict__ C,
    float* __restrict__ stats) {
    __shared__ ushort zt[16 * 128];     // 4 KB, swizzled: byte ^= (row&7)<<4
    __shared__ float lstat[256];
    int tid = threadIdx.x;
    int n = tid >> 4;                   // local row 0..15
    int c = tid & 15;                   // 16B chunk of the 256B row
    int idx = blockIdx.x * 16 + n;
    int node = perm[idx];
    int2 oo = off2p[idx];
    const short8* hb8 = (const short8*)hb;

    U8 sv; sv.v = hb8[(size_t)node * 16 + c];
    float acc[8];
#pragma unroll
    for (int k = 0; k < 8; k++) acc[k] = b2f(sv.u[k]);

    int e = oo.x, e1 = oo.y;
    for (; e + 8 <= e1; e += 8) {
        int s[8];
#pragma unroll
        for (int j = 0; j < 8; j++) s[j] = adj[e + j];
        U8 u[8];
#pragma unroll
        for (int j = 0; j < 8; j++) u[j].v = hb8[(size_t)s[j] * 16 + c];
#pragma unroll
        for (int j = 0; j < 8; j++)
#pragma unroll
            for (int k = 0; k < 8; k++) acc[k] += b2f(u[j].u[k]);
    }
    for (; e + 4 <= e1; e += 4) {
        int s0 = adj[e], s1 = adj[e + 1], s2 = adj[e + 2], s3 = adj[e + 3];
        U8 u0, u1, u2, u3;
        u0.v = hb8[(size_t)s0 * 16 + c];
        u1.v = hb8[(size_t)s1 * 16 + c];
        u2.v = hb8[(size_t)s2 * 16 + c];
        u3.v = hb8[(size_t)s3 * 16 + c];
#pragma unroll
        for (int k = 0; k < 8; k++)
            acc[k] += (b2f(u0.u[k]) + b2f(u1.u[k])) + (b2f(u2.u[k]) + b2f(u3.u[k]));
    }
    for (; e < e1; e++) {
        int s = adj[e];
        U8 u; u.v = hb8[(size_t)s * 16 + c];
#pragma unroll
        for (int k = 0; k < 8; k++) acc[k] += b2f(u.u[k]);
    }

    U8 o;
#pragma unroll
    for (int k = 0; k < 8; k++) o.u[k] = f2b(acc[k]);
    *(short8*)((char*)zt + ((n * 256 + c * 16) ^ ((n & 7) << 4))) = o.v;
    __syncthreads();

    // ---- GEMM epilogue: wave w -> output cols 32w..32w+31 for all 16 rows --
    int wave = tid >> 6;
    int lane = tid & 63;
    int q = lane >> 4;
    int l16 = lane & 15;

    f32x4 gacc[2];
    gacc[0] = (f32x4){0.f, 0.f, 0.f, 0.f};
    gacc[1] = (f32x4){0.f, 0.f, 0.f, 0.f};

#pragma unroll
    for (int kc = 0; kc < 4; kc++) {
        int k0 = kc * 32 + q * 8;
        int ch = kc * 4 + q;
        short8 av = *(const short8*)(
            (char*)zt + ((l16 * 256 + ch * 16) ^ ((l16 & 7) << 4)));
#pragma unroll
        for (int nt = 0; nt < 2; nt++) {
            int col0 = (wave * 2 + nt) * 16;
            short8 bf = *(const short8*)&WT[(size_t)(col0 + l16) * 128 + k0];
            gacc[nt] = __builtin_amdgcn_mfma_f32_16x16x32_bf16(
                av, bf, gacc[nt], 0, 0, 0);
        }
    }

    int rowbase = blockIdx.x * 16;
    int prow[4];
#pragma unroll
    for (int r = 0; r < 4; r++) prow[r] = perm[rowbase + q * 4 + r];
#pragma unroll
    for (int nt = 0; nt < 2; nt++) {
        int col = (wave * 2 + nt) * 16 + l16;
        float b = bias[col];
        float csum = 0.f, csq = 0.f;
#pragma unroll
        for (int r = 0; r < 4; r++) {
            float v = gacc[nt][r] + b;
            C[(size_t)prow[r] * 128 + col] = f2b(v);
            csum += v; csq += v * v;
        }
        csum += __shfl_xor(csum, 16, 64); csq += __shfl_xor(csq, 16, 64);
        csum += __shfl_xor(csum, 32, 64); csq += __shfl_xor(csq, 32, 64);
        if (q == 0) { lstat[col] = csum; lstat[128 + col] = csq; }
    }
    __syncthreads();
    atomicAdd(&stats[((blockIdx.x & (NREP1 - 1)) << 8) + tid], lstat[tid]);
}

// --------- GEMM2: 64 rows/block + LDS-staged WT (high-occupancy form) -------
__global__ __launch_bounds__(256) void k_gemm2(
    const ushort* __restrict__ A, const unsigned short* __restrict__ WT,
    const float* __restrict__ bias, ushort* __restrict__ C,
    const float* __restrict__ statsIn, const float* __restrict__ gamma,
    const float* __restrict__ beta, float* __restrict__ stats) {
    __shared__ ushort wlds[16384];       // 32 KB WT tile, XOR-swizzled
    __shared__ float lstat[256];
    __shared__ float s_sc[128], s_sh[128];
    int tid = threadIdx.x;

    // stage WT -> LDS (swizzled, coalesced; 8 short8 per thread)
#pragma unroll
    for (int it = 0; it < 8; it++) {
        int i = tid * 8 + it * 2048;     // ushort index
        int row = i >> 7;
        short8 v = *(const short8*)&WT[i];
        *(short8*)((char*)wlds + ((i * 2) ^ ((row & 7) << 4))) = v;
    }

    if (tid < 128) {
        float s = 0.f, qq = 0.f;
#pragma unroll
        for (int r = 0; r < NREP1; r++) {
            s  += statsIn[r * 256 + tid];
            qq += statsIn[r * 256 + 128 + tid];
        }
        float m = s * (1.f / NNODES);
        float var = qq * (1.f / NNODES) - m * m;
        float sc = gamma[tid] * rsqrtf(var + BN_EPS);
        s_sc[tid] = sc;
        s_sh[tid] = beta[tid] - m * sc;
    }
    lstat[tid] = 0.f;

    int wave = tid >> 6;
    int lane = tid & 63;
    int q = lane >> 4;
    int l16 = lane & 15;
    int rowbase = blockIdx.x * 64 + wave * 16;

    // prefetch all A fragments (4 independent VMEM loads, one latency)
    int arow = rowbase + l16;
    if (arow >= NNODES) arow = NNODES - 1;
    short8 araw[4];
#pragma unroll
    for (int kc = 0; kc < 4; kc++)
        araw[kc] = *(const short8*)&A[(size_t)arow * 128 + kc * 32 + q * 8];

    f32x4 acc[8];
#pragma unroll
    for (int nt = 0; nt < 8; nt++) acc[nt] = (f32x4){0.f, 0.f, 0.f, 0.f};

    __syncthreads();   // wlds + s_sc/s_sh ready

#pragma unroll
    for (int kc = 0; kc < 4; kc++) {
        int k0 = kc * 32 + q * 8;
        short8 bf[8];
#pragma unroll
        for (int nt = 0; nt < 8; nt++) {
            int row = nt * 16 + l16;
            bf[nt] = *(const short8*)(
                (char*)wlds + ((row * 256 + k0 * 2) ^ ((row & 7) << 4)));
        }

        float4 s0 = *(const float4*)&s_sc[k0];
        float4 s1 = *(const float4*)&s_sc[k0 + 4];
        float4 t0 = *(const float4*)&s_sh[k0];
        float4 t1 = *(const float4*)&s_sh[k0 + 4];
        float scl[8] = {s0.x, s0.y, s0.z, s0.w, s1.x, s1.y, s1.z, s1.w};
        float shf[8] = {t0.x, t0.y, t0.z, t0.w, t1.x, t1.y, t1.z, t1.w};
        union { short8 s; unsigned short u[8]; } in, cv;
        in.s = araw[kc];
#pragma unroll
        for (int j = 0; j < 8; j++) {
            float f = fmaxf(b2f(in.u[j]) * scl[j] + shf[j], 0.f);
            cv.u[j] = f2b(f);
        }
#pragma unroll
        for (int nt = 0; nt < 8; nt++)
            acc[nt] = __builtin_amdgcn_mfma_f32_16x16x32_bf16(
                cv.s, bf[nt], acc[nt], 0, 0, 0);
    }

#pragma unroll
    for (int nt = 0; nt < 8; nt++) {
        float b = bias[nt * 16 + l16];
        float csum = 0.f, csq = 0.f;
        int rb = rowbase + q * 4;
#pragma unroll
        for (int r = 0; r < 4; r++) {
            int row = rb + r;
            if (row < NNODES) {
                float v = acc[nt][r] + b;
                C[(size_t)row * 128 + nt * 16 + l16] = f2b(v);
                csum += v; csq += v * v;
            }
        }
        csum += __shfl_xor(csum, 16, 64); csq += __shfl_xor(csq, 16, 64);
        csum += __shfl_xor(csum, 32, 64); csq += __shfl_xor(csq, 32, 64);
        if (q == 0) {
            atomicAdd(&lstat[nt * 16 + l16], csum);
            atomicAdd(&lstat[128 + nt * 16 + l16], csq);
        }
    }
    __syncthreads();
    atomicAdd(&stats[((blockIdx.x & (NREP2 - 1)) << 8) + tid], lstat[tid]);
}

// ---- resid: h += relu(BN2(t2b)); hb = bf16(h) ------------------------------
__global__ void k_resid(float* __restrict__ h, ushort* __restrict__ hb,
                        const ushort* __restrict__ t2b,
                        const float* __restrict__ statsIn,
                        const float* __restrict__ gamma, const float* __restrict__ beta) {
    __shared__ float s_sc[128], s_sh[128];
    int tid = threadIdx.x;
    if (tid < 128) {
        float s = 0.f, qq = 0.f;
#pragma unroll
        for (int r = 0; r < NREP2; r++) {
            s  += statsIn[r * 256 + tid];
            qq += statsIn[r * 256 + 128 + tid];
        }
        float m = s * (1.f / NNODES);
        float var = qq * (1.f / NNODES) - m * m;
        float sc = gamma[tid] * rsqrtf(var + BN_EPS);
        s_sc[tid] = sc;
        s_sh[tid] = beta[tid] - m * sc;
    }
    __syncthreads();
    int i = blockIdx.x * 256 + tid;
    int c4 = (i & 31) * 4;
    float4 sc = *(const float4*)&s_sc[c4];
    float4 sh = *(const float4*)&s_sh[c4];
    ushort4 t = ((const ushort4*)t2b)[i];
    float4 hv = ((float4*)h)[i];
    hv.x += fmaxf(b2f(t.x) * sc.x + sh.x, 0.f);
    hv.y += fmaxf(b2f(t.y) * sc.y + sh.y, 0.f);
    hv.z += fmaxf(b2f(t.z) * sc.z + sh.z, 0.f);
    hv.w += fmaxf(b2f(t.w) * sc.w + sh.w, 0.f);
    ((float4*)h)[i] = hv;
    ushort4 o;
    o.x = f2b(hv.x); o.y = f2b(hv.y); o.z = f2b(hv.z); o.w = f2b(hv.w);
    ((ushort4*)hb)[i] = o;
}

// ---------------- pooling (with count histogram) + projection ----------------
__global__ void k_pool(const float* __restrict__ h, const int* __restrict__ batch,
                       float* __restrict__ pooled, float* __restrict__ gcnt) {
    __shared__ float4 red[256];
    __shared__ int lcnt[NGRAPHS];
    int t = threadIdx.x;
    int d4 = t & 31, sub = t >> 5;
    int n0 = blockIdx.x * 128;
    if (n0 >= NNODES) return;
    int n1 = n0 + 128; if (n1 > NNODES) n1 = NNODES;
    if (t < NGRAPHS) lcnt[t] = 0;
    __syncthreads();
    if (t < n1 - n0) atomicAdd(&lcnt[batch[n0 + t]], 1);
    __syncthreads();
    if (t < NGRAPHS && lcnt[t]) atomicAdd(&gcnt[t], (float)lcnt[t]);

    int glo = batch[n0], ghi = batch[n1 - 1];
    for (int g = glo; g <= ghi; g++) {
        float4 acc = make_float4(0.f, 0.f, 0.f, 0.f);
        for (int r = n0 + sub; r < n1; r += 8) {
            if (batch[r] == g) {
                float4 v = ((const float4*)h)[(size_t)r * 32 + d4];
                acc.x += v.x; acc.y += v.y; acc.z += v.z; acc.w += v.w;
            }
        }
        red[t] = acc;
        __syncthreads();
        if (sub < 4) {
            float4 o = red[t + 128];
            red[t].x += o.x; red[t].y += o.y; red[t].z += o.z; red[t].w += o.w;
        }
        __syncthreads();
        if (sub < 2) {
            float4 o = red[t + 64];
            red[t].x += o.x; red[t].y += o.y; red[t].z += o.z; red[t].w += o.w;
        }
        __syncthreads();
        if (sub == 0) {
            float4 o = red[t + 32];
            float4 a = red[t];
            a.x += o.x; a.y += o.y; a.z += o.z; a.w += o.w;
            atomicAdd(&pooled[g * 128 + d4 * 4 + 0], a.x);
            atomicAdd(&pooled[g * 128 + d4 * 4 + 1], a.y);
            atomicAdd(&pooled[g * 128 + d4 * 4 + 2], a.z);
            atomicAdd(&pooled[g * 128 + d4 * 4 + 3], a.w);
        }
        __syncthreads();
    }
}

__global__ void k_proj(const float* __restrict__ pooled, const float* __restrict__ cnt,
                       const float* __restrict__ wp, const float* __restrict__ bp,
                       float* __restrict__ out) {
    __shared__ float prow[128];
    int g = blockIdx.x, c = threadIdx.x;
    if (c < 128) prow[c] = pooled[g * 128 + c] / fmaxf(cnt[g], 1.f);
    __syncthreads();
    float acc = bp[c];
    for (int k = 0; k < 128; k++) acc += prow[k] * wp[k * 256 + c];
    out[g * 256 + c] = acc;
}

extern "C" void kernel_launch(void* const* d_in, const int* in_sizes, int n_in,
                              void* d_out, int out_size, void* d_ws, size_t ws_size,
                              hipStream_t stream) {
    const float* x    = (const float*)d_in[0];
    const int*   eidx = (const int*)d_in[1];
    const int*   batch= (const int*)d_in[2];
    const float* w1   = (const float*)d_in[3];
    const float* b1   = (const float*)d_in[4];
    const float* g1   = (const float*)d_in[5];
    const float* be1  = (const float*)d_in[6];
    const float* w2   = (const float*)d_in[7];
    const float* b2   = (const float*)d_in[8];
    const float* gbn  = (const float*)d_in[9];
    const float* bbn  = (const float*)d_in[10];
    const float* wp   = (const float*)d_in[11];
    const float* bp   = (const float*)d_in[12];

    float* out  = (float*)d_out;
    float* gemb = out;                          // [64,256]
    float* h    = out + (size_t)NGRAPHS * OUTD; // node_emb lives in d_out

    char* w = (char*)d_ws;
    ushort* hb   = (ushort*)w; w += (size_t)NNODES * 128 * 2; // bf16 mirror of h
    ushort* t2b  = (ushort*)w; w += (size_t)NNODES * 128 * 2; // bf16 t2
    ushort* tb   = (ushort*)w; w += (size_t)NNODES * 128 * 2; // bf16 t
    int2*  off2  = (int2*)w;  w += (size_t)NNODES * 8;
    int*   adj   = (int*)w;   w += (size_t)NBUCK * BUCKCAP * 4;
    unsigned short* WT = (unsigned short*)w; w += (size_t)10 * 16384 * 2;
    int*   bcur  = (int*)w;   w += 256 * 4;
    // per layer: NREP1*256 (stats1) + NREP2*256 (stats2)
    float* statsAll = (float*)w; w += (size_t)NLAYERS * (NREP1 + NREP2) * 256 * 4;
    float* pooled= (float*)w; w += (size_t)NGRAPHS * HID * 4;
    float* gcnt  = (float*)w; w += NGRAPHS * 4;
    int*   dhist = (int*)w;   w += 1024 * 4;   // padded 64 bins (stride 16)
    int*   dcur  = (int*)w;   w += 1024 * 4;   // padded cursors
    int*   perm  = (int*)w;   w += (size_t)NNODES * 4;
    int2*  off2p = (int2*)w;  w += (size_t)NNODES * 8;

    // packed edge buffer aliases tb (dead until layer loop)
    unsigned int* packed = (unsigned int*)tb;

    const int* srcv = eidx;
    const int* dstv = eidx + NEDGES;

    // h = x, hb = bf16(x), W transposes, bcur init (one launch)
    k_init<<<12500 + 640, 256, 0, stream>>>(x, h, hb, w1, w2, WT, bcur);

    // zero stats replicas + pooled + gcnt + dhist + dcur in one shot
    hipMemsetAsync(statsAll, 0,
                   ((size_t)NLAYERS * (NREP1 + NREP2) * 256 + NGRAPHS * HID + NGRAPHS
                    + 2048) * 4, stream);

    // CSR build + degree-sorted (ascending) permutation
    k_fill1<<<FILL_BLOCKS, 256, 0, stream>>>(srcv, dstv, bcur, packed);
    k_fill2<<<NBUCK, 256, 0, stream>>>(packed, bcur, off2, adj, dhist);
    k_dscan<<<1, 64, 0, stream>>>(dhist, dcur);
    k_dscat<<<(NNODES + 255) / 256, 256, 0, stream>>>(off2, dcur, perm, off2p);

    for (int i = 0; i < NLAYERS; i++) {
        float* st1 = statsAll + (size_t)i * (NREP1 + NREP2) * 256;
        float* st2 = st1 + (size_t)NREP1 * 256;
        k_ag1<<<AG1B, 256, 0, stream>>>(
            hb, off2p, adj, perm, WT + (size_t)i * 16384, b1 + i * HID, tb, st1);
        k_gemm2<<<G2B, 256, 0, stream>>>(
            tb, WT + (size_t)(5 + i) * 16384, b2 + i * HID, t2b,
            st1, g1 + i * HID, be1 + i * HID, st2);
        k_resid<<<NNODES * 128 / 4 / 256, 256, 0, stream>>>(
            h, hb, t2b, st2, gbn + i * HID, bbn + i * HID);
    }

    // pooling (+counts) + projection
    k_pool<<<(NNODES + 127) / 128, 256, 0, stream>>>(h, batch, pooled, gcnt);
    k_proj<<<NGRAPHS, 256, 0, stream>>>(pooled, gcnt, wp, bp, gemb);
}